// Round 10
// baseline (2991.474 us; speedup 1.0000x reference)
//
#include <hip/hip_runtime.h>
#include <hip/hip_cooperative_groups.h>
#include <math.h>

namespace cg = cooperative_groups;

// Problem constants (from reference)
#define DD 128
#define SS 255          // 2*D-1 shift candidates
#define HDIM 1024
#define CDIM 128
#define NPOS 4096       // B*T = 8*512
#define TEMPER 0.85f
#define ENERGY_TH 0.01f
#define NBLK 256
#define RPB 16          // rows per block (NPOS / NBLK), one row per wave

// ===========================================================================
// MEGA KERNEL (cooperative): 256 blocks x 1024 threads (16 waves = 4/SIMD).
// Block b owns rows [16b,16b+16): wave w handles row 16b+w in phase A.
// Parity (it&1) double-buffers energy/maskp/scal/selcnt (verified r7 logic).
// scal layout: [0,1]=sd(p) [2,3]=cnt(p) [4,5]=lossh_raw(p) [6]=total accum
// ===========================================================================
__global__ __launch_bounds__(1024)
void k_mega(const float* __restrict__ x, const float* __restrict__ y,
            const float* __restrict__ We, const float* __restrict__ Wd,
            float* __restrict__ xr, float* __restrict__ yr,
            float* __restrict__ Wes, float* __restrict__ Wds,
            float* __restrict__ energy,      // [2][HDIM]
            float* __restrict__ maskp,       // [2][HDIM]
            float* __restrict__ scal,        // [8]
            unsigned int* __restrict__ selcnt, // [2]
            float* __restrict__ out)
{
    cg::grid_group grid = cg::this_grid();
    const int b = blockIdx.x;
    const int t = threadIdx.x;
    const int w = t >> 6, l = t & 63;     // 16 waves, 64 lanes

    __shared__ __align__(16) float Vl[RPB][DD];      // 8 KB, persists per iter
    __shared__ __align__(16) float xsp[RPB][384];    // 24 KB zero-padded x
    __shared__ __align__(16) float vpad[RPB][384];   // 24 KB zero-padded v
    __shared__ __align__(16) float ysl[RPB][DD];     // 8 KB
    __shared__ float Pfl[RPB][DD];                   // 8 KB
    __shared__ __align__(16) float Hs[RPB][CDIM];    // 8 KB
    __shared__ float ren[RPB];
    __shared__ float redl[32];
    __shared__ float avL[HDIM];                      // 4 KB
    __shared__ unsigned int rkL[4];
    __shared__ int selSlot[4];
    __shared__ int selFlag[4];

    // ---------------- init: row-local copies + accumulator zeroing ---------
    {
        const int r0 = b * RPB;
        const float4* xs4g = (const float4*)(x + (size_t)r0 * DD);
        const float4* ys4g = (const float4*)(y + (size_t)r0 * DD);
        float4* xr4 = (float4*)(xr + (size_t)r0 * DD);
        float4* yr4 = (float4*)(yr + (size_t)r0 * DD);
        if (t < 512) { xr4[t] = xs4g[t]; yr4[t] = ys4g[t]; }
        if (t < 4) {
            energy[0 * HDIM + 4 * b + t] = 0.f;
            energy[1 * HDIM + 4 * b + t] = 0.f;
            maskp[1 * HDIM + 4 * b + t] = 0.f;   // parity-1 buffer read at it=0
        }
        if (b == 0) {
            if (t < 8) scal[t] = 0.f;
            if (t < 2) selcnt[t] = 0u;
        }
    }
    grid.sync();

    for (int it = 0; it < 8; ++it) {
        const int p = it & 1, pp = p ^ 1;

        // ================= PHASE A: align, one row per wave ===============
        {
            float* xs = xsp[w]; float* vp = vpad[w]; float* yw = ysl[w]; float* pf = Pfl[w];
            const int pos = b * RPB + w;

            // zero pads (0..126 and 255..383)
            for (int i = l; i < 127; i += 64)       { xs[i] = 0.f; vp[i] = 0.f; }
            for (int i = 255 + l; i < 384; i += 64) { xs[i] = 0.f; vp[i] = 0.f; }

            const float2 x2 = *(const float2*)(xr + (size_t)pos * DD + 2 * l);
            const float2 y2 = *(const float2*)(yr + (size_t)pos * DD + 2 * l);
            xs[127 + 2 * l] = x2.x; xs[128 + 2 * l] = x2.y;
            yw[2 * l] = y2.x; yw[2 * l + 1] = y2.y;

            // inclusive prefix sum of x^2 (2 elems/lane + wave scan)
            float a = x2.x * x2.x, bb = x2.y * x2.y;
            float c = a + bb;
            #pragma unroll
            for (int off = 1; off < 64; off <<= 1) {
                float n = __shfl_up(c, off);
                if (l >= off) c += n;
            }
            float excl = c - (a + bb);
            pf[2 * l] = excl + a;
            pf[2 * l + 1] = c;
            // ||y||^2
            float ynv = y2.x * y2.x + y2.y * y2.y;
            #pragma unroll
            for (int off = 32; off > 0; off >>= 1) ynv += __shfl_xor(ynv, off);
            __syncthreads();   // xs/yw/pf visible

            // correlation: shifts 4l..4l+3, float4 sliding window
            float acc0 = 0.f, acc1 = 0.f, acc2 = 0.f, acc3 = 0.f;
            const float4* xs4 = (const float4*)(xs + 4 * l);
            const float4* yw4 = (const float4*)yw;
            float4 xa = xs4[0];
            #pragma unroll 4
            for (int j = 0; j < 32; ++j) {
                float4 xb = xs4[j + 1];
                float4 yv = yw4[j];
                acc0 = fmaf(xa.x, yv.x, fmaf(xa.y, yv.y, fmaf(xa.z, yv.z, fmaf(xa.w, yv.w, acc0))));
                acc1 = fmaf(xa.y, yv.x, fmaf(xa.z, yv.y, fmaf(xa.w, yv.z, fmaf(xb.x, yv.w, acc1))));
                acc2 = fmaf(xa.z, yv.x, fmaf(xa.w, yv.y, fmaf(xb.x, yv.z, fmaf(xb.y, yv.w, acc2))));
                acc3 = fmaf(xa.w, yv.x, fmaf(xb.x, yv.y, fmaf(xb.y, yv.z, fmaf(xb.z, yv.w, acc3))));
                xa = xb;
            }
            // argmax (first-occurrence tie-break)
            float best = -INFINITY; int bidx = 0;
            float accs[4] = {acc0, acc1, acc2, acc3};
            #pragma unroll
            for (int q = 0; q < 4; ++q) {
                int s = 4 * l + q;
                float nrm2 = pf[s < DD ? s : DD - 1] - ((s >= DD) ? pf[s - DD] : 0.f);
                nrm2 = fmaxf(nrm2, 0.f);
                float denom = sqrtf(nrm2) * sqrtf(ynv);
                float sim = (denom > 0.f) ? accs[q] / fmaxf(denom, 1e-12f) : 0.f;
                if (s == SS) sim = -INFINITY;
                if (sim > best) { best = sim; bidx = s; }
            }
            #pragma unroll
            for (int off = 32; off > 0; off >>= 1) {
                float ov = __shfl_xor(best, off);
                int   oi = __shfl_xor(bidx, off);
                if (ov > best || (ov == best && oi < bidx)) { best = ov; bidx = oi; }
            }
            const int theta = bidx;

            // softmax attention (d = l and l+64)
            float ya0 = xs[theta + l], ya1 = xs[theta + l + 64];
            float z0 = ya0 * yw[l] / TEMPER;
            float z1 = ya1 * yw[l + 64] / TEMPER;
            float zm = fmaxf(z0, z1);
            #pragma unroll
            for (int off = 32; off > 0; off >>= 1) zm = fmaxf(zm, __shfl_xor(zm, off));
            float e0 = expf(z0 - zm), e1 = expf(z1 - zm);
            float es = e0 + e1;
            #pragma unroll
            for (int off = 32; off > 0; off >>= 1) es += __shfl_xor(es, off);
            float v0 = ya0 * (e0 / es);
            float v1 = ya1 * (e1 / es);
            vp[127 + l] = v0; vp[127 + l + 64] = v1;
            Vl[w][l] = v0;    Vl[w][l + 64] = v1;
            __syncthreads();   // vp + all Vl rows visible

            // reverse shift -> x_res update
            float xe0 = vp[l + 2 * (DD - 1) - theta];
            float xe1 = vp[l + 64 + 2 * (DD - 1) - theta];
            xr[(size_t)pos * DD + l]      = xs[127 + l] - xe0;
            xr[(size_t)pos * DD + l + 64] = xs[127 + l + 64] - xe1;
        }

        // ===== ENERGY: col j = t (1024 cols), 16 rows from LDS ============
        {
            const int j = t;
            float acc[RPB];
            #pragma unroll
            for (int r = 0; r < RPB; ++r) acc[r] = 0.f;

            for (int d0 = 0; d0 < DD; d0 += 4) {
                float w0 = We[(size_t)(d0 + 0) * HDIM + j];
                float w1 = We[(size_t)(d0 + 1) * HDIM + j];
                float w2 = We[(size_t)(d0 + 2) * HDIM + j];
                float w3 = We[(size_t)(d0 + 3) * HDIM + j];
                #pragma unroll
                for (int r = 0; r < RPB; ++r) {
                    float4 v = *(const float4*)(&Vl[r][d0]);
                    acc[r] = fmaf(v.x, w0, fmaf(v.y, w1, fmaf(v.z, w2, fmaf(v.w, w3, acc[r]))));
                }
            }
            float e = 0.f;
            #pragma unroll
            for (int r = 0; r < RPB; ++r) { float h = fmaxf(acc[r], 0.f); e = fmaf(h, h, e); }
            atomicAdd(&energy[p * HDIM + j], e);
        }
        grid.sync();   // ---- sync1: energies complete ----

        // ================= PHASE S: distributed exact top-128 =============
        {
            // stage masked values (one per thread)
            {
                float e = energy[p * HDIM + t];
                float m = maskp[pp * HDIM + t];
                avL[t] = (m > 0.f) ? -INFINITY : e;
            }
            if (t < 4) rkL[t] = 0u;
            __syncthreads();

            // rank this block's 4 elems (i0..i0+3) vs all 1024
            const int i0 = 4 * b;
            const int q  = t >> 8;        // elem 0..3 (4 waves each)
            const int tj = t & 255;
            const float avq = avL[i0 + q];
            unsigned int cnt = 0u;
            #pragma unroll
            for (int jj = 0; jj < 4; ++jj) {
                int j = tj + 256 * jj;
                float aj = avL[j];
                cnt += (aj > avq) || (aj == avq && j < i0 + q);
            }
            #pragma unroll
            for (int off = 32; off > 0; off >>= 1) cnt += __shfl_xor(cnt, off);
            if (l == 0 && cnt) atomicAdd(&rkL[q], cnt);
            __syncthreads();

            if (t < 4) {
                const int i = i0 + t;
                const bool masked = (avL[i] == -INFINITY);
                const bool sel = (rkL[t] < 128u) && !masked;
                maskp[p * HDIM + i] = (masked || sel) ? 1.f : 0.f;   // cumulative (>0 test)
                energy[pp * HDIM + i] = 0.f;                          // ready for next phaseA
                int slot = -1;
                if (sel) slot = (int)atomicAdd(&selcnt[p], 1u);
                selFlag[t] = sel ? 1 : 0;
                selSlot[t] = slot;
                if (!sel) atomicAdd(&scal[4 + p], energy[p * HDIM + i]);  // raw lossh sum
            }
            // finalize PREVIOUS iteration's loss (prev-parity slots only)
            if (b == 0 && t == 0) {
                scal[6] += scal[0 + pp] / fmaxf(scal[2 + pp], 1.f)
                         + scal[4 + pp] * (1.f / (4096.f * 1024.f));
                scal[0 + pp] = 0.f; scal[2 + pp] = 0.f; scal[4 + pp] = 0.f;
                selcnt[pp] = 0u;
            }
            __syncthreads();   // selFlag/selSlot visible

            // gather compacted weight columns (4 elems in parallel)
            {
                const int tt = t & 255;
                if (selFlag[q]) {
                    const int i = i0 + q, slot = selSlot[q];
                    if (tt < 128) Wes[(size_t)tt * CDIM + slot] = We[(size_t)tt * HDIM + i];
                    else { int d = tt - 128; Wds[(size_t)slot * DD + d] = Wd[(size_t)i * DD + d]; }
                }
            }
        }
        grid.sync();   // ---- sync2: Wes/Wds complete ----

        // ================= DECODE: y_ele + masked MSE + y_res -= ==========
        {
            const int r0g = b * RPB;
            // row energies of y_res (pre-update); wave w computes ren[w]
            {
                const float2 yv = *(const float2*)(yr + (size_t)(r0g + w) * DD + 2 * l);
                float s = yv.x * yv.x + yv.y * yv.y;
                #pragma unroll
                for (int off = 32; off > 0; off >>= 1) s += __shfl_xor(s, off);
                if (l == 0) ren[w] = s * (1.f / (float)DD);
            }
            const int k = t & 127, rg = t >> 7;   // 8 groups x 2 rows

            // phase 1: Hs = relu(V @ Wes)
            float acc1[2] = {0.f, 0.f};
            for (int d0 = 0; d0 < DD; d0 += 4) {
                float w0 = Wes[(size_t)(d0 + 0) * CDIM + k];
                float w1 = Wes[(size_t)(d0 + 1) * CDIM + k];
                float w2 = Wes[(size_t)(d0 + 2) * CDIM + k];
                float w3 = Wes[(size_t)(d0 + 3) * CDIM + k];
                #pragma unroll
                for (int r = 0; r < 2; ++r) {
                    float4 v = *(const float4*)(&Vl[rg * 2 + r][d0]);
                    acc1[r] = fmaf(v.x, w0, fmaf(v.y, w1, fmaf(v.z, w2, fmaf(v.w, w3, acc1[r]))));
                }
            }
            Hs[rg * 2 + 0][k] = fmaxf(acc1[0], 0.f);
            Hs[rg * 2 + 1][k] = fmaxf(acc1[1], 0.f);
            __syncthreads();   // Hs + ren visible

            // phase 2: y_ele = Hs @ Wds; fused loss + residual update
            float acc2[2] = {0.f, 0.f};
            for (int k0 = 0; k0 < CDIM; k0 += 4) {
                float w0 = Wds[(size_t)(k0 + 0) * DD + k];
                float w1 = Wds[(size_t)(k0 + 1) * DD + k];
                float w2 = Wds[(size_t)(k0 + 2) * DD + k];
                float w3 = Wds[(size_t)(k0 + 3) * DD + k];
                #pragma unroll
                for (int r = 0; r < 2; ++r) {
                    float4 h = *(const float4*)(&Hs[rg * 2 + r][k0]);
                    acc2[r] = fmaf(h.x, w0, fmaf(h.y, w1, fmaf(h.z, w2, fmaf(h.w, w3, acc2[r]))));
                }
            }
            float sd = 0.f, sv = 0.f;
            #pragma unroll
            for (int r = 0; r < 2; ++r) {
                const int row = r0g + rg * 2 + r;
                float tgt = yr[(size_t)row * DD + k];
                float yo  = y [(size_t)row * DD + k];
                bool valid = (yo != 0.f) && (ren[rg * 2 + r] > ENERGY_TH);
                float diff = acc2[r] - tgt;
                if (valid) { sd = fmaf(diff, diff, sd); sv += 1.f; }
                yr[(size_t)row * DD + k] = tgt - acc2[r];
            }
            // block reduce -> scal atomics (current parity)
            #pragma unroll
            for (int off = 32; off > 0; off >>= 1) { sd += __shfl_xor(sd, off); sv += __shfl_xor(sv, off); }
            if (l == 0) { redl[w] = sd; redl[16 + w] = sv; }
            __syncthreads();
            if (t == 0) {
                float ssd = 0.f, ssv = 0.f;
                #pragma unroll
                for (int q2 = 0; q2 < 16; ++q2) { ssd += redl[q2]; ssv += redl[16 + q2]; }
                atomicAdd(&scal[0 + p], ssd);
                atomicAdd(&scal[2 + p], ssv);
            }
            __threadfence_block();
            __syncthreads();   // yr/Vl reuse safe before next align
        }
        // no grid sync here: next iter's sync1 orders scal/Wes cross-block deps
    }
    grid.sync();
    if (b == 0 && t == 0) {
        // finalize iteration 7 (parity 1)
        float total = scal[6] + scal[1] / fmaxf(scal[3], 1.f)
                    + scal[5] * (1.f / (4096.f * 1024.f));
        out[0] = total * 0.125f;
    }
}

// ===========================================================================
// FALLBACK PATH (round-5 multi-kernel, known-passing @728us) — used only if
// the cooperative launch is rejected.
// ===========================================================================
__global__ __launch_bounds__(256) void k_init(const float* __restrict__ x, const float* __restrict__ y,
                                              float* __restrict__ xr, float* __restrict__ yr,
                                              float* __restrict__ energy, float* __restrict__ maskp,
                                              float* __restrict__ scal) {
    int gid = blockIdx.x * 256 + threadIdx.x;
    for (int i = gid; i < NPOS * DD; i += gridDim.x * 256) { xr[i] = x[i]; yr[i] = y[i]; }
    if (gid < HDIM) { energy[gid] = 0.f; maskp[gid] = 0.f; }
    if (gid < 8)    { scal[gid] = 0.f; }
}

__global__ __launch_bounds__(256) void k_align(float* __restrict__ xr_g, const float* __restrict__ yr_g,
                                               float* __restrict__ V_g) {
    __shared__ __align__(16) float xsp[4][384];
    __shared__ __align__(16) float vpad[4][384];
    __shared__ __align__(16) float ysl[4][128];
    __shared__ float Pfl[4][128];

    const int t = threadIdx.x;
    const int w = t >> 6, l = t & 63;
    const int pos = blockIdx.x * 4 + w;

    float* xs = xsp[w]; float* vp = vpad[w]; float* yw = ysl[w]; float* pf = Pfl[w];

    for (int i = l; i < 127; i += 64) { xs[i] = 0.f; vp[i] = 0.f; }
    for (int i = 255 + l; i < 384; i += 64) { xs[i] = 0.f; vp[i] = 0.f; }

    const float2 x2 = *(const float2*)(xr_g + pos * DD + 2 * l);
    const float2 y2 = *(const float2*)(yr_g + pos * DD + 2 * l);
    xs[127 + 2 * l] = x2.x; xs[128 + 2 * l] = x2.y;
    yw[2 * l] = y2.x; yw[2 * l + 1] = y2.y;

    float a = x2.x * x2.x, b = x2.y * x2.y;
    float c = a + b;
    #pragma unroll
    for (int off = 1; off < 64; off <<= 1) {
        float n = __shfl_up(c, off);
        if (l >= off) c += n;
    }
    float excl = c - (a + b);
    pf[2 * l] = excl + a;
    pf[2 * l + 1] = c;

    float yn = y2.x * y2.x + y2.y * y2.y;
    #pragma unroll
    for (int off = 32; off > 0; off >>= 1) yn += __shfl_xor(yn, off);
    __syncthreads();

    float acc0 = 0.f, acc1 = 0.f, acc2 = 0.f, acc3 = 0.f;
    const float4* xs4 = (const float4*)(xs + 4 * l);
    const float4* yw4 = (const float4*)yw;
    float4 xa = xs4[0];
    #pragma unroll 4
    for (int j = 0; j < 32; ++j) {
        float4 xb = xs4[j + 1];
        float4 yv = yw4[j];
        acc0 = fmaf(xa.x, yv.x, fmaf(xa.y, yv.y, fmaf(xa.z, yv.z, fmaf(xa.w, yv.w, acc0))));
        acc1 = fmaf(xa.y, yv.x, fmaf(xa.z, yv.y, fmaf(xa.w, yv.z, fmaf(xb.x, yv.w, acc1))));
        acc2 = fmaf(xa.z, yv.x, fmaf(xa.w, yv.y, fmaf(xb.x, yv.z, fmaf(xb.y, yv.w, acc2))));
        acc3 = fmaf(xa.w, yv.x, fmaf(xb.x, yv.y, fmaf(xb.y, yv.z, fmaf(xb.z, yv.w, acc3))));
        xa = xb;
    }

    float best = -INFINITY; int bidx = 0;
    float accs[4] = {acc0, acc1, acc2, acc3};
    #pragma unroll
    for (int q = 0; q < 4; ++q) {
        int s = 4 * l + q;
        float nrm2 = pf[s < DD ? s : DD - 1] - ((s >= DD) ? pf[s - DD] : 0.f);
        nrm2 = fmaxf(nrm2, 0.f);
        float denom = sqrtf(nrm2) * sqrtf(yn);
        float sim = (denom > 0.f) ? accs[q] / fmaxf(denom, 1e-12f) : 0.f;
        if (s == SS) sim = -INFINITY;
        if (sim > best) { best = sim; bidx = s; }
    }
    #pragma unroll
    for (int off = 32; off > 0; off >>= 1) {
        float ov = __shfl_xor(best, off);
        int   oi = __shfl_xor(bidx, off);
        if (ov > best || (ov == best && oi < bidx)) { best = ov; bidx = oi; }
    }
    const int theta = bidx;

    const int d0 = l, d1 = l + 64;
    float ya0 = xs[theta + d0], ya1 = xs[theta + d1];
    float z0 = ya0 * yw[d0] / TEMPER;
    float z1 = ya1 * yw[d1] / TEMPER;
    float zm = fmaxf(z0, z1);
    #pragma unroll
    for (int off = 32; off > 0; off >>= 1) zm = fmaxf(zm, __shfl_xor(zm, off));
    float e0 = expf(z0 - zm), e1 = expf(z1 - zm);
    float es = e0 + e1;
    #pragma unroll
    for (int off = 32; off > 0; off >>= 1) es += __shfl_xor(es, off);
    float v0 = ya0 * (e0 / es);
    float v1 = ya1 * (e1 / es);
    vp[127 + d0] = v0; vp[127 + d1] = v1;
    V_g[pos * DD + d0] = v0; V_g[pos * DD + d1] = v1;
    __syncthreads();

    float xe0 = vp[d0 + 2 * (DD - 1) - theta];
    float xe1 = vp[d1 + 2 * (DD - 1) - theta];
    xr_g[pos * DD + d0] = xs[127 + d0] - xe0;
    xr_g[pos * DD + d1] = xs[127 + d1] - xe1;
}

#define FMT 64
__global__ __launch_bounds__(256) void k_energy(const float* __restrict__ V_g, const float* __restrict__ We,
                                                float* __restrict__ energy) {
    __shared__ __align__(16) float Vl[FMT][DD];
    const int t  = threadIdx.x;
    const int tx = t & 63;
    const int ty = t >> 6;
    const int m0 = blockIdx.x * FMT;
    const int n0 = blockIdx.y * 256;
    const int j  = n0 + tx * 4;
    const int r0 = ty * 16;

    const float4* v4 = (const float4*)(V_g + m0 * DD);
    float4* vl4 = (float4*)(&Vl[0][0]);
    #pragma unroll
    for (int i = 0; i < 8; ++i) vl4[t + 256 * i] = v4[t + 256 * i];
    __syncthreads();

    float acc[16][4];
    #pragma unroll
    for (int r = 0; r < 16; ++r)
        #pragma unroll
        for (int cc = 0; cc < 4; ++cc) acc[r][cc] = 0.f;

    for (int d0 = 0; d0 < DD; d0 += 4) {
        float wreg[4][4];
        #pragma unroll
        for (int dd = 0; dd < 4; ++dd) {
            float4 wa = *(const float4*)(We + (d0 + dd) * HDIM + j);
            wreg[dd][0] = wa.x; wreg[dd][1] = wa.y; wreg[dd][2] = wa.z; wreg[dd][3] = wa.w;
        }
        #pragma unroll
        for (int r = 0; r < 16; ++r) {
            float4 v = *(const float4*)(&Vl[r0 + r][d0]);
            float vv[4] = {v.x, v.y, v.z, v.w};
            #pragma unroll
            for (int dd = 0; dd < 4; ++dd)
                #pragma unroll
                for (int cc = 0; cc < 4; ++cc)
                    acc[r][cc] = fmaf(vv[dd], wreg[dd][cc], acc[r][cc]);
        }
    }

    __syncthreads();
    float* Ps = &Vl[0][0];
    #pragma unroll
    for (int cc = 0; cc < 4; ++cc) {
        float e = 0.f;
        #pragma unroll
        for (int r = 0; r < 16; ++r) { float h = fmaxf(acc[r][cc], 0.f); e = fmaf(h, h, e); }
        Ps[ty * 256 + tx * 4 + cc] = e;
    }
    __syncthreads();
    float esum = 0.f;
    #pragma unroll
    for (int q = 0; q < 4; ++q) esum += Ps[q * 256 + t];
    atomicAdd(&energy[n0 + t], esum);
}

__global__ __launch_bounds__(1024) void k_select(float* __restrict__ energy, float* __restrict__ maskp,
                                                 float* __restrict__ scal,
                                                 const float* __restrict__ We, const float* __restrict__ Wd,
                                                 float* __restrict__ Wes, float* __restrict__ Wds, int iter) {
    __shared__ float sv[HDIM];
    __shared__ int   si[HDIM];
    __shared__ int   mk[HDIM];
    __shared__ float red[HDIM];
    __shared__ int   sel_l[CDIM];

    const int t = threadIdx.x;
    if (t == 0) {
        if (iter > 0) scal[3] += scal[0] / fmaxf(scal[1], 1.f) + scal[2];
        scal[0] = 0.f; scal[1] = 0.f;
    }
    float e = energy[t] * (1.0f / (float)NPOS);
    sv[t] = (maskp[t] > 0.f) ? -INFINITY : e;
    si[t] = t;
    __syncthreads();

    for (int k = 2; k <= HDIM; k <<= 1) {
        for (int j = k >> 1; j > 0; j >>= 1) {
            int ixj = t ^ j;
            if (ixj > t) {
                bool up = ((t & k) == 0);
                float va = sv[t], vb = sv[ixj];
                int ia = si[t], ib = si[ixj];
                bool inorder = (va > vb) || (va == vb && ia < ib);
                if (up != inorder) { sv[t] = vb; si[t] = ib; sv[ixj] = va; si[ixj] = ia; }
            }
            __syncthreads();
        }
    }

    mk[t] = 0;
    __syncthreads();
    if (t < CDIM) { mk[si[t]] = 1; sel_l[t] = si[t]; }
    __syncthreads();
    const int mym = mk[t];

    red[t] = e;
    __syncthreads();
    for (int off = 512; off > 0; off >>= 1) { if (t < off) red[t] += red[t + off]; __syncthreads(); }
    const float sum_all = red[0];
    __syncthreads();
    red[t] = mym ? e : 0.f;
    __syncthreads();
    for (int off = 512; off > 0; off >>= 1) { if (t < off) red[t] += red[t + off]; __syncthreads(); }
    const float sum_sel = red[0];
    if (t == 0) scal[2] = (sum_all - sum_sel) / (float)HDIM;

    maskp[t] = maskp[t] + (float)mym;
    energy[t] = 0.f;
    __syncthreads();

    for (int i = t; i < DD * CDIM; i += HDIM) {
        int d = i >> 7, kk = i & 127;
        Wes[i] = We[d * HDIM + sel_l[kk]];
    }
    for (int i = t; i < CDIM * DD; i += HDIM) {
        int kk = i >> 7, d = i & 127;
        Wds[i] = Wd[sel_l[kk] * DD + d];
    }
}

#define RT 32
__global__ __launch_bounds__(256) void k_decode(const float* __restrict__ V_g, const float* __restrict__ Wes,
                                                const float* __restrict__ Wds, float* __restrict__ yr_g,
                                                const float* __restrict__ y_orig, float* __restrict__ scal) {
    __shared__ __align__(16) float Vl[RT][DD];
    __shared__ __align__(16) float Hs[RT][CDIM];
    __shared__ float ren[RT];
    __shared__ float redf[256];

    const int t = threadIdx.x;
    const int r0 = blockIdx.x * RT;

    const float4* v4 = (const float4*)(V_g + r0 * DD);
    float4* vl4 = (float4*)(&Vl[0][0]);
    #pragma unroll
    for (int i = 0; i < 4; ++i) vl4[t + 256 * i] = v4[t + 256 * i];

    {
        int r = t >> 3, lane8 = t & 7;
        float s = 0.f;
        const float* yp = yr_g + (r0 + r) * DD + lane8 * 16;
        #pragma unroll
        for (int c = 0; c < 16; ++c) { float v = yp[c]; s = fmaf(v, v, s); }
        s += __shfl_xor(s, 1); s += __shfl_xor(s, 2); s += __shfl_xor(s, 4);
        if (lane8 == 0) ren[r] = s * (1.f / (float)DD);
    }
    __syncthreads();

    const int half = t >> 7;
    const int k = t & 127;

    {
        float acc[16];
        #pragma unroll
        for (int r = 0; r < 16; ++r) acc[r] = 0.f;
        for (int d0 = 0; d0 < DD; d0 += 4) {
            float w0 = Wes[(d0 + 0) * CDIM + k];
            float w1 = Wes[(d0 + 1) * CDIM + k];
            float w2 = Wes[(d0 + 2) * CDIM + k];
            float w3 = Wes[(d0 + 3) * CDIM + k];
            #pragma unroll
            for (int r = 0; r < 16; ++r) {
                float4 v = *(const float4*)(&Vl[half * 16 + r][d0]);
                acc[r] = fmaf(v.x, w0, fmaf(v.y, w1, fmaf(v.z, w2, fmaf(v.w, w3, acc[r]))));
            }
        }
        #pragma unroll
        for (int r = 0; r < 16; ++r) Hs[half * 16 + r][k] = fmaxf(acc[r], 0.f);
    }
    __syncthreads();

    {
        float acc[16];
        #pragma unroll
        for (int r = 0; r < 16; ++r) acc[r] = 0.f;
        for (int k0 = 0; k0 < CDIM; k0 += 4) {
            float w0 = Wds[(k0 + 0) * DD + k];
            float w1 = Wds[(k0 + 1) * DD + k];
            float w2 = Wds[(k0 + 2) * DD + k];
            float w3 = Wds[(k0 + 3) * DD + k];
            #pragma unroll
            for (int r = 0; r < 16; ++r) {
                float4 h = *(const float4*)(&Hs[half * 16 + r][k0]);
                acc[r] = fmaf(h.x, w0, fmaf(h.y, w1, fmaf(h.z, w2, fmaf(h.w, w3, acc[r]))));
            }
        }
        float sd = 0.f, svld = 0.f;
        #pragma unroll
        for (int r = 0; r < 16; ++r) {
            int row = r0 + half * 16 + r;
            float tgt = yr_g[row * DD + k];
            float yo  = y_orig[row * DD + k];
            bool valid = (yo != 0.f) && (ren[half * 16 + r] > ENERGY_TH);
            float diff = acc[r] - tgt;
            if (valid) { sd = fmaf(diff, diff, sd); svld += 1.f; }
            yr_g[row * DD + k] = tgt - acc[r];
        }
        redf[t] = sd;
        __syncthreads();
        for (int off = 128; off > 0; off >>= 1) { if (t < off) redf[t] += redf[t + off]; __syncthreads(); }
        if (t == 0) atomicAdd(&scal[0], redf[0]);
        __syncthreads();
        redf[t] = svld;
        __syncthreads();
        for (int off = 128; off > 0; off >>= 1) { if (t < off) redf[t] += redf[t + off]; __syncthreads(); }
        if (t == 0) atomicAdd(&scal[1], redf[0]);
    }
}

__global__ void k_final(const float* __restrict__ scal, float* __restrict__ out) {
    float total = scal[3] + scal[0] / fmaxf(scal[1], 1.f) + scal[2];
    out[0] = total * (1.f / 8.f);
}

// ===========================================================================
extern "C" void kernel_launch(void* const* d_in, const int* in_sizes, int n_in,
                              void* d_out, int out_size, void* d_ws, size_t ws_size,
                              hipStream_t stream) {
    const float* x  = (const float*)d_in[0];
    const float* y  = (const float*)d_in[1];
    const float* We = (const float*)d_in[2];
    const float* Wd = (const float*)d_in[3];

    float* ws     = (float*)d_ws;
    // shared by both paths
    float* xr     = ws;                     // 524288
    float* yr     = ws + 524288;            // 524288
    float* Wes    = ws + 1048576;           // 16384
    float* Wds    = ws + 1064960;           // 16384
    // mega-only accumulators
    float* energy = ws + 1081344;           // 2048 (2 x 1024)
    float* maskp  = ws + 1083392;           // 2048
    float* scal   = ws + 1085440;           // 8
    unsigned int* selcnt = (unsigned int*)(ws + 1085448); // 2
    // fallback-only arrays — OVERLAP the mega-only region (exactly one path
    // runs per call, and each path fully initializes what it touches).
    float* V       = ws + 1081344;          // 524288 -> ..1605632
    float* fenergy = ws + 1605632;          // 1024
    float* fmaskp  = ws + 1606656;          // 1024
    float* fscal   = ws + 1607680;          // 8 -> total 1607688 < proven 1607816
    float* out    = (float*)d_out;

    void* args[] = {
        (void*)&x, (void*)&y, (void*)&We, (void*)&Wd,
        (void*)&xr, (void*)&yr, (void*)&Wes, (void*)&Wds,
        (void*)&energy, (void*)&maskp, (void*)&scal, (void*)&selcnt,
        (void*)&out
    };
    hipError_t err = hipLaunchCooperativeKernel((const void*)k_mega, dim3(NBLK),
                                                dim3(1024), args, 0u, stream);
    if (err != hipSuccess) {
        (void)hipGetLastError();   // clear sticky error, use fallback path
        k_init<<<2048, 256, 0, stream>>>(x, y, xr, yr, fenergy, fmaskp, fscal);
        for (int it = 0; it < 8; ++it) {
            k_align<<<NPOS / 4, 256, 0, stream>>>(xr, yr, V);
            k_energy<<<dim3(NPOS / FMT, HDIM / 256), 256, 0, stream>>>(V, We, fenergy);
            k_select<<<1, 1024, 0, stream>>>(fenergy, fmaskp, fscal, We, Wd, Wes, Wds, it);
            k_decode<<<NPOS / RT, 256, 0, stream>>>(V, Wes, Wds, yr, y, fscal);
        }
        k_final<<<1, 1, 0, stream>>>(fscal, out);
    }
}

// Round 12
// 919.226 us; speedup vs baseline: 3.2543x; 3.2543x over previous
//
#include <hip/hip_runtime.h>
#include <math.h>

#define DD 128
#define SS 255          // 2*D-1 shift candidates
#define HDIM 1024
#define CDIM 128
#define NPOS 4096       // B*T
#define TEMPER 0.85f
#define ENERGY_TH 0.01f
#define FMT 64          // energy tile rows

// ---------------------------------------------------------------------------
// init: zero accumulators only (1 block)
// ---------------------------------------------------------------------------
__global__ __launch_bounds__(1024) void k_init0(float* __restrict__ energy, float* __restrict__ maskp,
                                                float* __restrict__ scal, unsigned int* __restrict__ counter) {
    const int t = threadIdx.x;
    energy[t] = 0.f; maskp[t] = 0.f;
    if (t < 8) { scal[t] = 0.f; counter[t] = 0u; }
}

// ---------------------------------------------------------------------------
// align0 (iteration 0): reads x,y; writes xr (=x residual after it0) and V.
// r5-verified body. 1024 blocks x 256 thr, 4 positions/block (1/wave).
// ---------------------------------------------------------------------------
__global__ __launch_bounds__(256) void k_align0(const float* __restrict__ x_in, const float* __restrict__ y_in,
                                                float* __restrict__ xr_g, float* __restrict__ V_g) {
    __shared__ __align__(16) float xsp[4][384];
    __shared__ __align__(16) float vpad[4][384];
    __shared__ __align__(16) float ysl[4][128];
    __shared__ float Pfl[4][128];

    const int t = threadIdx.x;
    const int w = t >> 6, l = t & 63;
    const int pos = blockIdx.x * 4 + w;

    float* xs = xsp[w]; float* vp = vpad[w]; float* yw = ysl[w]; float* pf = Pfl[w];

    for (int i = l; i < 127; i += 64) { xs[i] = 0.f; vp[i] = 0.f; }
    for (int i = 255 + l; i < 384; i += 64) { xs[i] = 0.f; vp[i] = 0.f; }

    const float2 x2 = *(const float2*)(x_in + (size_t)pos * DD + 2 * l);
    const float2 y2 = *(const float2*)(y_in + (size_t)pos * DD + 2 * l);
    xs[127 + 2 * l] = x2.x; xs[128 + 2 * l] = x2.y;
    yw[2 * l] = y2.x; yw[2 * l + 1] = y2.y;

    float a = x2.x * x2.x, b = x2.y * x2.y;
    float c = a + b;
    #pragma unroll
    for (int off = 1; off < 64; off <<= 1) {
        float n = __shfl_up(c, off);
        if (l >= off) c += n;
    }
    float excl = c - (a + b);
    pf[2 * l] = excl + a;
    pf[2 * l + 1] = c;

    float yn = y2.x * y2.x + y2.y * y2.y;
    #pragma unroll
    for (int off = 32; off > 0; off >>= 1) yn += __shfl_xor(yn, off);
    __syncthreads();

    float acc0 = 0.f, acc1 = 0.f, acc2 = 0.f, acc3 = 0.f;
    const float4* xs4 = (const float4*)(xs + 4 * l);
    const float4* yw4 = (const float4*)yw;
    float4 xa = xs4[0];
    #pragma unroll 4
    for (int j = 0; j < 32; ++j) {
        float4 xb = xs4[j + 1];
        float4 yv = yw4[j];
        acc0 = fmaf(xa.x, yv.x, fmaf(xa.y, yv.y, fmaf(xa.z, yv.z, fmaf(xa.w, yv.w, acc0))));
        acc1 = fmaf(xa.y, yv.x, fmaf(xa.z, yv.y, fmaf(xa.w, yv.z, fmaf(xb.x, yv.w, acc1))));
        acc2 = fmaf(xa.z, yv.x, fmaf(xa.w, yv.y, fmaf(xb.x, yv.z, fmaf(xb.y, yv.w, acc2))));
        acc3 = fmaf(xa.w, yv.x, fmaf(xb.x, yv.y, fmaf(xb.y, yv.z, fmaf(xb.z, yv.w, acc3))));
        xa = xb;
    }

    float best = -INFINITY; int bidx = 0;
    float accs[4] = {acc0, acc1, acc2, acc3};
    #pragma unroll
    for (int q = 0; q < 4; ++q) {
        int s = 4 * l + q;
        float nrm2 = pf[s < DD ? s : DD - 1] - ((s >= DD) ? pf[s - DD] : 0.f);
        nrm2 = fmaxf(nrm2, 0.f);
        float denom = sqrtf(nrm2) * sqrtf(yn);
        float sim = (denom > 0.f) ? accs[q] / fmaxf(denom, 1e-12f) : 0.f;
        if (s == SS) sim = -INFINITY;
        if (sim > best) { best = sim; bidx = s; }
    }
    #pragma unroll
    for (int off = 32; off > 0; off >>= 1) {
        float ov = __shfl_xor(best, off);
        int   oi = __shfl_xor(bidx, off);
        if (ov > best || (ov == best && oi < bidx)) { best = ov; bidx = oi; }
    }
    const int theta = bidx;

    const int d0 = l, d1 = l + 64;
    float ya0 = xs[theta + d0], ya1 = xs[theta + d1];
    float z0 = ya0 * yw[d0] / TEMPER;
    float z1 = ya1 * yw[d1] / TEMPER;
    float zm = fmaxf(z0, z1);
    #pragma unroll
    for (int off = 32; off > 0; off >>= 1) zm = fmaxf(zm, __shfl_xor(zm, off));
    float e0 = expf(z0 - zm), e1 = expf(z1 - zm);
    float es = e0 + e1;
    #pragma unroll
    for (int off = 32; off > 0; off >>= 1) es += __shfl_xor(es, off);
    float v0 = ya0 * (e0 / es);
    float v1 = ya1 * (e1 / es);
    vp[127 + d0] = v0; vp[127 + d1] = v1;
    V_g[(size_t)pos * DD + d0] = v0; V_g[(size_t)pos * DD + d1] = v1;
    __syncthreads();

    float xe0 = vp[d0 + 2 * (DD - 1) - theta];
    float xe1 = vp[d1 + 2 * (DD - 1) - theta];
    xr_g[(size_t)pos * DD + d0] = xs[127 + d0] - xe0;
    xr_g[(size_t)pos * DD + d1] = xs[127 + d1] - xe1;
}

// ---------------------------------------------------------------------------
// k_es: energy (r5 FMT=64 tile, grid (64,4)) + last-block top-128 selection.
// counter = per-iteration slot (zeroed in k_init0, no reset race).
// ---------------------------------------------------------------------------
__global__ __launch_bounds__(256) void k_es(const float* __restrict__ V_g, const float* __restrict__ We,
                                            const float* __restrict__ Wd,
                                            float* __restrict__ energy, float* __restrict__ maskp,
                                            float* __restrict__ scal,
                                            float* __restrict__ Wes, float* __restrict__ Wds,
                                            unsigned int* __restrict__ counter, int iter) {
    __shared__ __align__(16) float Vl[FMT][DD];   // 32 KB; reused by select
    const int t  = threadIdx.x;
    const int tx = t & 63;
    const int ty = t >> 6;
    const int m0 = blockIdx.x * FMT;
    const int n0 = blockIdx.y * 256;
    const int j  = n0 + tx * 4;
    const int r0 = ty * 16;

    const float4* v4 = (const float4*)(V_g + (size_t)m0 * DD);
    float4* vl4 = (float4*)(&Vl[0][0]);
    #pragma unroll
    for (int i = 0; i < 8; ++i) vl4[t + 256 * i] = v4[t + 256 * i];
    __syncthreads();

    float acc[16][4];
    #pragma unroll
    for (int r = 0; r < 16; ++r)
        #pragma unroll
        for (int cc = 0; cc < 4; ++cc) acc[r][cc] = 0.f;

    for (int d0 = 0; d0 < DD; d0 += 4) {
        float wreg[4][4];
        #pragma unroll
        for (int dd = 0; dd < 4; ++dd) {
            float4 wa = *(const float4*)(We + (size_t)(d0 + dd) * HDIM + j);
            wreg[dd][0] = wa.x; wreg[dd][1] = wa.y; wreg[dd][2] = wa.z; wreg[dd][3] = wa.w;
        }
        #pragma unroll
        for (int r = 0; r < 16; ++r) {
            float4 v = *(const float4*)(&Vl[r0 + r][d0]);
            float vv[4] = {v.x, v.y, v.z, v.w};
            #pragma unroll
            for (int dd = 0; dd < 4; ++dd)
                #pragma unroll
                for (int cc = 0; cc < 4; ++cc)
                    acc[r][cc] = fmaf(vv[dd], wreg[dd][cc], acc[r][cc]);
        }
    }

    __syncthreads();
    float* Ps = &Vl[0][0];
    #pragma unroll
    for (int cc = 0; cc < 4; ++cc) {
        float e = 0.f;
        #pragma unroll
        for (int r = 0; r < 16; ++r) { float h = fmaxf(acc[r][cc], 0.f); e = fmaf(h, h, e); }
        Ps[ty * 256 + tx * 4 + cc] = e;
    }
    __syncthreads();
    float esum = 0.f;
    #pragma unroll
    for (int q = 0; q < 4; ++q) esum += Ps[q * 256 + t];
    atomicAdd(&energy[n0 + t], esum);

    // ------------- last-block-done: selection -------------
    __threadfence();
    __shared__ unsigned int lastFlag;
    if (t == 0) {
        unsigned int prev = atomicAdd(counter, 1u);
        lastFlag = (prev == 64u * 4u - 1u) ? 1u : 0u;
    }
    __syncthreads();
    if (!lastFlag) return;

    // carve LDS from Vl (energy phase done): sv[1024], si[1024], ev[1024], red[256]
    float* sv = &Vl[0][0];
    int*   si = (int*)&Vl[8][0];
    float* ev = &Vl[16][0];
    float* red = &Vl[24][0];
    __shared__ int sel_l[CDIM];

    // finalize PREVIOUS iteration's loss (r5 k_select logic), reset sd/cnt
    if (t == 0) {
        if (iter > 0) scal[3] += scal[0] / fmaxf(scal[1], 1.f) + scal[2];
        scal[0] = 0.f; scal[1] = 0.f;
    }
    // load energies via atomic read (cross-XCD coherent), mask, index init
    #pragma unroll
    for (int q = 0; q < 4; ++q) {
        int i = t + 256 * q;
        float e = atomicAdd(&energy[i], 0.f) * (1.0f / (float)NPOS);
        ev[i] = e;
        sv[i] = (maskp[i] > 0.f) ? -INFINITY : e;
        si[i] = i;
    }
    __syncthreads();

    // bitonic sort, 256 threads x 4 elements (r5-verified comparator)
    for (int k = 2; k <= HDIM; k <<= 1) {
        for (int jj = k >> 1; jj > 0; jj >>= 1) {
            #pragma unroll
            for (int q = 0; q < 4; ++q) {
                int e = t + 256 * q;
                int ixj = e ^ jj;
                if (ixj > e) {
                    bool up = ((e & k) == 0);
                    float va = sv[e], vb = sv[ixj];
                    int ia = si[e], ib = si[ixj];
                    bool inorder = (va > vb) || (va == vb && ia < ib);
                    if (up != inorder) { sv[e] = vb; si[e] = ib; sv[ixj] = va; si[ixj] = ia; }
                }
            }
            __syncthreads();
        }
    }

    // top-128 -> sel_l; cumulative mask; energy reset for next iteration
    if (t < CDIM) {
        int s = si[t];
        sel_l[t] = s;
        maskp[s] = maskp[s] + 1.f;       // scatter, unique indices
    }
    #pragma unroll
    for (int q = 0; q < 4; ++q) energy[t + 256 * q] = 0.f;

    // loss_h = (sum_all - sum_sel)/HDIM
    float pa = 0.f;
    #pragma unroll
    for (int q = 0; q < 4; ++q) pa += ev[t + 256 * q];
    red[t] = pa;
    __syncthreads();
    for (int off = 128; off > 0; off >>= 1) { if (t < off) red[t] += red[t + off]; __syncthreads(); }
    const float sum_all = red[0];
    __syncthreads();
    red[t] = (t < CDIM) ? ev[sel_l[t]] : 0.f;
    __syncthreads();
    for (int off = 128; off > 0; off >>= 1) { if (t < off) red[t] += red[t + off]; __syncthreads(); }
    if (t == 0) scal[2] = (sum_all - red[0]) / (float)HDIM;
    __syncthreads();

    // gather compacted weights
    for (int i = t; i < DD * CDIM; i += 256) {
        int d = i >> 7, kk = i & 127;
        Wes[i] = We[(size_t)d * HDIM + sel_l[kk]];
    }
    for (int i = t; i < CDIM * DD; i += 256) {
        int kk = i >> 7, d = i & 127;
        Wds[i] = Wd[(size_t)sel_l[kk] * DD + d];
    }
}

// ---------------------------------------------------------------------------
// k_da<FIRST, DO_ALIGN>: decode (16 rows/block) then align(it+1) for the same
// rows. y_res passes decode->align through LDS yblk. 256 blocks x 256 thr.
// ---------------------------------------------------------------------------
template<int FIRST, int DO_ALIGN>
__global__ __launch_bounds__(256) void k_da(const float* __restrict__ V_g, const float* __restrict__ Wes,
                                            const float* __restrict__ Wds, float* __restrict__ yr_g,
                                            const float* __restrict__ y_orig, float* __restrict__ scal,
                                            float* __restrict__ xr_g, float* __restrict__ V_out) {
    __shared__ __align__(16) float Vl[16][DD];     // 8 KB
    __shared__ __align__(16) float Hs[16][CDIM];   // 8 KB
    __shared__ __align__(16) float yblk[16][DD];   // 8 KB (new y_res)
    __shared__ float ren[16];
    __shared__ float redf[256];
    __shared__ __align__(16) float xsp[4][384];    // align scratch
    __shared__ __align__(16) float vpad[4][384];
    __shared__ float Pfl[4][128];

    const int t = threadIdx.x, w = t >> 6, l = t & 63;
    const int r0 = blockIdx.x * 16;
    const float* ycur = FIRST ? y_orig : yr_g;

    const float4* v4 = (const float4*)(V_g + (size_t)r0 * DD);
    float4* vl4 = (float4*)(&Vl[0][0]);
    vl4[t] = v4[t]; vl4[t + 256] = v4[t + 256];

    // row energies of current y_res
    {
        int r = t >> 4, ln = t & 15;
        float s = 0.f;
        const float* yp = ycur + (size_t)(r0 + r) * DD + ln * 8;
        #pragma unroll
        for (int c = 0; c < 8; ++c) { float v = yp[c]; s = fmaf(v, v, s); }
        s += __shfl_xor(s, 1); s += __shfl_xor(s, 2); s += __shfl_xor(s, 4); s += __shfl_xor(s, 8);
        if (ln == 0) ren[r] = s * (1.f / (float)DD);
    }
    __syncthreads();

    const int half = t >> 7;      // 2 groups x 8 rows
    const int k = t & 127;

    // phase 1: Hs = relu(V @ Wes)
    {
        float acc[8];
        #pragma unroll
        for (int r = 0; r < 8; ++r) acc[r] = 0.f;
        for (int d0 = 0; d0 < DD; d0 += 4) {
            float w0 = Wes[(size_t)(d0 + 0) * CDIM + k];
            float w1 = Wes[(size_t)(d0 + 1) * CDIM + k];
            float w2 = Wes[(size_t)(d0 + 2) * CDIM + k];
            float w3 = Wes[(size_t)(d0 + 3) * CDIM + k];
            #pragma unroll
            for (int r = 0; r < 8; ++r) {
                float4 v = *(const float4*)(&Vl[half * 8 + r][d0]);
                acc[r] = fmaf(v.x, w0, fmaf(v.y, w1, fmaf(v.z, w2, fmaf(v.w, w3, acc[r]))));
            }
        }
        #pragma unroll
        for (int r = 0; r < 8; ++r) Hs[half * 8 + r][k] = fmaxf(acc[r], 0.f);
    }
    __syncthreads();

    // phase 2: y_ele; fused loss + y_res update (global + LDS)
    {
        float acc[8];
        #pragma unroll
        for (int r = 0; r < 8; ++r) acc[r] = 0.f;
        for (int k0 = 0; k0 < CDIM; k0 += 4) {
            float w0 = Wds[(size_t)(k0 + 0) * DD + k];
            float w1 = Wds[(size_t)(k0 + 1) * DD + k];
            float w2 = Wds[(size_t)(k0 + 2) * DD + k];
            float w3 = Wds[(size_t)(k0 + 3) * DD + k];
            #pragma unroll
            for (int r = 0; r < 8; ++r) {
                float4 h = *(const float4*)(&Hs[half * 8 + r][k0]);
                acc[r] = fmaf(h.x, w0, fmaf(h.y, w1, fmaf(h.z, w2, fmaf(h.w, w3, acc[r]))));
            }
        }
        float sd = 0.f, sv = 0.f;
        #pragma unroll
        for (int r = 0; r < 8; ++r) {
            const int row = r0 + half * 8 + r;
            float tgt = ycur[(size_t)row * DD + k];
            float yo  = y_orig[(size_t)row * DD + k];
            bool valid = (yo != 0.f) && (ren[half * 8 + r] > ENERGY_TH);
            float diff = acc[r] - tgt;
            if (valid) { sd = fmaf(diff, diff, sd); sv += 1.f; }
            float ny = tgt - acc[r];
            yr_g[(size_t)row * DD + k] = ny;
            yblk[half * 8 + r][k] = ny;
        }
        redf[t] = sd;
        __syncthreads();
        for (int off = 128; off > 0; off >>= 1) { if (t < off) redf[t] += redf[t + off]; __syncthreads(); }
        if (t == 0) atomicAdd(&scal[0], redf[0]);
        __syncthreads();
        redf[t] = sv;
        __syncthreads();
        for (int off = 128; off > 0; off >>= 1) { if (t < off) redf[t] += redf[t + off]; __syncthreads(); }
        if (t == 0) atomicAdd(&scal[1], redf[0]);
        __syncthreads();   // yblk complete + reductions done
    }

    if (DO_ALIGN) {
        float* xs = xsp[w]; float* vp = vpad[w]; float* pf = Pfl[w];
        for (int i = l; i < 127; i += 64) { xs[i] = 0.f; vp[i] = 0.f; }
        for (int i = 255 + l; i < 384; i += 64) { xs[i] = 0.f; vp[i] = 0.f; }

        for (int pq = 0; pq < 4; ++pq) {
            const int r = 4 * w + pq;
            const int pos = r0 + r;
            const float* yw = yblk[r];
            const float2 x2 = *(const float2*)(xr_g + (size_t)pos * DD + 2 * l);
            xs[127 + 2 * l] = x2.x; xs[128 + 2 * l] = x2.y;
            const float y0v = yw[2 * l], y1v = yw[2 * l + 1];

            float a = x2.x * x2.x, bb = x2.y * x2.y;
            float c = a + bb;
            #pragma unroll
            for (int off = 1; off < 64; off <<= 1) {
                float n = __shfl_up(c, off);
                if (l >= off) c += n;
            }
            float excl = c - (a + bb);
            pf[2 * l] = excl + a;
            pf[2 * l + 1] = c;
            float ynv = y0v * y0v + y1v * y1v;
            #pragma unroll
            for (int off = 32; off > 0; off >>= 1) ynv += __shfl_xor(ynv, off);
            __syncthreads();

            float acc0 = 0.f, acc1 = 0.f, acc2 = 0.f, acc3 = 0.f;
            const float4* xs4 = (const float4*)(xs + 4 * l);
            const float4* yw4 = (const float4*)yw;
            float4 xa = xs4[0];
            #pragma unroll 4
            for (int jj = 0; jj < 32; ++jj) {
                float4 xb = xs4[jj + 1];
                float4 yv = yw4[jj];
                acc0 = fmaf(xa.x, yv.x, fmaf(xa.y, yv.y, fmaf(xa.z, yv.z, fmaf(xa.w, yv.w, acc0))));
                acc1 = fmaf(xa.y, yv.x, fmaf(xa.z, yv.y, fmaf(xa.w, yv.z, fmaf(xb.x, yv.w, acc1))));
                acc2 = fmaf(xa.z, yv.x, fmaf(xa.w, yv.y, fmaf(xb.x, yv.z, fmaf(xb.y, yv.w, acc2))));
                acc3 = fmaf(xa.w, yv.x, fmaf(xb.x, yv.y, fmaf(xb.y, yv.z, fmaf(xb.z, yv.w, acc3))));
                xa = xb;
            }
            float best = -INFINITY; int bidx = 0;
            float accs[4] = {acc0, acc1, acc2, acc3};
            #pragma unroll
            for (int q = 0; q < 4; ++q) {
                int s = 4 * l + q;
                float nrm2 = pf[s < DD ? s : DD - 1] - ((s >= DD) ? pf[s - DD] : 0.f);
                nrm2 = fmaxf(nrm2, 0.f);
                float denom = sqrtf(nrm2) * sqrtf(ynv);
                float sim = (denom > 0.f) ? accs[q] / fmaxf(denom, 1e-12f) : 0.f;
                if (s == SS) sim = -INFINITY;
                if (sim > best) { best = sim; bidx = s; }
            }
            #pragma unroll
            for (int off = 32; off > 0; off >>= 1) {
                float ov = __shfl_xor(best, off);
                int   oi = __shfl_xor(bidx, off);
                if (ov > best || (ov == best && oi < bidx)) { best = ov; bidx = oi; }
            }
            const int theta = bidx;

            float ya0 = xs[theta + l], ya1 = xs[theta + l + 64];
            float z0 = ya0 * yw[l] / TEMPER;
            float z1 = ya1 * yw[l + 64] / TEMPER;
            float zm = fmaxf(z0, z1);
            #pragma unroll
            for (int off = 32; off > 0; off >>= 1) zm = fmaxf(zm, __shfl_xor(zm, off));
            float e0 = expf(z0 - zm), e1 = expf(z1 - zm);
            float es = e0 + e1;
            #pragma unroll
            for (int off = 32; off > 0; off >>= 1) es += __shfl_xor(es, off);
            float v0 = ya0 * (e0 / es);
            float v1 = ya1 * (e1 / es);
            vp[127 + l] = v0; vp[127 + l + 64] = v1;
            V_out[(size_t)pos * DD + l] = v0;
            V_out[(size_t)pos * DD + l + 64] = v1;
            __syncthreads();

            float xe0 = vp[l + 2 * (DD - 1) - theta];
            float xe1 = vp[l + 64 + 2 * (DD - 1) - theta];
            xr_g[(size_t)pos * DD + l]      = xs[127 + l] - xe0;
            xr_g[(size_t)pos * DD + l + 64] = xs[127 + l + 64] - xe1;
            __syncthreads();
        }
    }
}

// ---------------------------------------------------------------------------
__global__ void k_final(const float* __restrict__ scal, float* __restrict__ out) {
    float total = scal[3] + scal[0] / fmaxf(scal[1], 1.f) + scal[2];
    out[0] = total * (1.f / 8.f);
}

extern "C" void kernel_launch(void* const* d_in, const int* in_sizes, int n_in,
                              void* d_out, int out_size, void* d_ws, size_t ws_size,
                              hipStream_t stream) {
    const float* x  = (const float*)d_in[0];
    const float* y  = (const float*)d_in[1];
    const float* We = (const float*)d_in[2];
    const float* Wd = (const float*)d_in[3];

    float* ws     = (float*)d_ws;
    float* xr     = ws;                     // 524288
    float* yr     = ws + 524288;            // 524288
    float* V      = ws + 1048576;           // 524288
    float* Wes    = ws + 1572864;           // 16384
    float* Wds    = ws + 1589248;           // 16384
    float* energy = ws + 1605632;           // 1024
    float* maskp  = ws + 1606656;           // 1024
    float* scal   = ws + 1607680;           // 8
    unsigned int* counter = (unsigned int*)(ws + 1607688); // 8
    float* out    = (float*)d_out;

    k_init0<<<1, 1024, 0, stream>>>(energy, maskp, scal, counter);
    k_align0<<<NPOS / 4, 256, 0, stream>>>(x, y, xr, V);
    for (int it = 0; it < 8; ++it) {
        k_es<<<dim3(NPOS / FMT, HDIM / 256), 256, 0, stream>>>(V, We, Wd, energy, maskp,
                                                               scal, Wes, Wds, counter + it, it);
        if (it == 0)      k_da<1, 1><<<NPOS / 16, 256, 0, stream>>>(V, Wes, Wds, yr, y, scal, xr, V);
        else if (it < 7)  k_da<0, 1><<<NPOS / 16, 256, 0, stream>>>(V, Wes, Wds, yr, y, scal, xr, V);
        else              k_da<0, 0><<<NPOS / 16, 256, 0, stream>>>(V, Wes, Wds, yr, y, scal, xr, V);
    }
    k_final<<<1, 1, 0, stream>>>(scal, out);
}